// Round 2
// baseline (17570.319 us; speedup 1.0000x reference)
//
#include <hip/hip_runtime.h>

// ---------------------------------------------------------------------------
// StackedLstm: 2-layer highway LSTM, B=64, T=512, D=H=1024
// Runtime dtype detection (bf16 vs fp32 inputs/outputs); internals bf16+fp32.
// pi computed in 8 time-chunks of 64 steps to keep workspace ~231 MB.
// ---------------------------------------------------------------------------

#define DEVINL __device__ __forceinline__

typedef short short8v __attribute__((ext_vector_type(8)));
typedef short short4v __attribute__((ext_vector_type(4)));
typedef float f32x4 __attribute__((ext_vector_type(4)));

#define Bsz   64
#define Tlen  512
#define Hdim  1024
#define NH5   5120
#define NH6   6144
#define TCH   64          // time-chunk length
#define NCH   8           // chunks per layer
#define XELT  33554432    // B*T*H elements

// d_out element offsets: y1 [B,T,H] | final_h [2,B,H] | final_c [2,B,H]
#define OUT_FH 33554432
#define OUT_FC 33685504

// workspace byte offsets (total ~231.2 MB)
#define WS_XBF    0ULL
#define WS_Y0     67108864ULL
#define WS_WIT0   134217728ULL
#define WS_WIT1   146800640ULL
#define WS_WST0   159383552ULL
#define WS_WST1   169869312ULL
#define WS_PI     180355072ULL
#define WS_HB0    230686720ULL
#define WS_HB1    230817792ULL
#define WS_CB     230948864ULL
#define WS_FLAGS  231211008ULL
#define WS_DFLAG  231212032ULL

DEVINL short f2bf(float f) {
  unsigned int u = __builtin_bit_cast(unsigned int, f);
  u += 0x7fffu + ((u >> 16) & 1u);          // round-to-nearest-even
  return (short)(u >> 16);
}
DEVINL float bf2f(short s) {
  unsigned int u = ((unsigned int)(unsigned short)s) << 16;
  return __builtin_bit_cast(float, u);
}
DEVINL float fexp2(float x) { return __builtin_amdgcn_exp2f(x); }
DEVINL float frcp(float x)  { return __builtin_amdgcn_rcpf(x); }
DEVINL float sigm(float x)  { return frcp(1.0f + fexp2(-1.44269504f * x)); }
DEVINL float tanh_(float x) { return 1.0f - 2.0f * frcp(1.0f + fexp2(2.88539008f * x)); }

DEVINL void gld_lds16(const short* g, short* lds) {
  __builtin_amdgcn_global_load_lds(
      (const __attribute__((address_space(1))) void*)g,
      (__attribute__((address_space(3))) void*)lds, 16, 0, 0);
}

// ---------------------------------------------------------------------------
// Detect input dtype: bf16 N(0,1) data never has exp==0xFF shorts; fp32 words
// read as shorts hit it with P ~ 1/256 per word. Also zeroes barrier flags.
__global__ void k_detect(const short* __restrict__ x, unsigned int* flags, int* dflag) {
  __shared__ int found;
  if (threadIdx.x == 0) found = 0;
  __syncthreads();
  int hit = 0;
  for (int i = threadIdx.x; i < 16384; i += 256) {
    unsigned int u = (unsigned short)x[i];
    if ((u & 0x7F80u) == 0x7F80u) hit = 1;
  }
  if (hit) atomicOr(&found, 1);
  flags[threadIdx.x] = 0;
  __syncthreads();
  if (threadIdx.x == 0) *dflag = found;
}

// x -> bf16 copy (converting from fp32 if detected)
__global__ void k_convert(const void* __restrict__ xin, short* __restrict__ xbf,
                          const int* __restrict__ dflag) {
  const int f32 = *dflag;
  const size_t stride = (size_t)gridDim.x * 1024;
  size_t i = ((size_t)blockIdx.x * 256 + threadIdx.x) * 4;
  for (; i < (size_t)XELT; i += stride) {
    short4v v;
    if (f32) {
      const float4 f = *(const float4*)&((const float*)xin)[i];
      v[0] = f2bf(f.x); v[1] = f2bf(f.y); v[2] = f2bf(f.z); v[3] = f2bf(f.w);
    } else {
      v = *(const short4v*)&((const short*)xin)[i];
    }
    *(short4v*)&xbf[i] = v;
  }
}

// (R,C) -> (C,R) bf16 output, dtype-flagged input, 64x64 tiles
__global__ void k_transpose(const void* __restrict__ in, short* __restrict__ out,
                            int R, int C, const int* __restrict__ dflag) {
  __shared__ short tile[64][65];
  const int f32 = *dflag;
  const int r0 = blockIdx.x << 6, c0 = blockIdx.y << 6;
  const int tid = threadIdx.x;
#pragma unroll
  for (int it = 0; it < 8; ++it) {
    int idx = (it << 8) + tid;
    int r = idx >> 5, c2 = (idx & 31) << 1;
    if (f32) {
      const float* inF = (const float*)in;
      tile[r][c2]     = f2bf(inF[(size_t)(r0 + r) * C + c0 + c2]);
      tile[r][c2 + 1] = f2bf(inF[(size_t)(r0 + r) * C + c0 + c2 + 1]);
    } else {
      int v = *(const int*)&((const short*)in)[(size_t)(r0 + r) * C + c0 + c2];
      tile[r][c2]     = (short)(v & 0xffff);
      tile[r][c2 + 1] = (short)(((unsigned)v) >> 16);
    }
  }
  __syncthreads();
#pragma unroll
  for (int it = 0; it < 8; ++it) {
    int idx = (it << 8) + tid;
    int rr = idx >> 5, k2 = (idx & 31) << 1;
    unsigned int lo = (unsigned short)tile[k2][rr];
    unsigned int hi = (unsigned short)tile[k2 + 1][rr];
    *(unsigned int*)&out[(size_t)(c0 + rr) * R + r0 + k2] = lo | (hi << 16);
  }
}

// ---------------------------------------------------------------------------
// pi_chunk[r, 0:6144] = A[row(r), :] @ Bt^T, r in [0,4096), row(r) maps the
// chunk's (b, t0+tt) rows. 128x128 tile, BK=64, global_load_lds + XOR swizzle.
__launch_bounds__(256)
__global__ void k_gemm(const short* __restrict__ A, const short* __restrict__ Bt,
                       short* __restrict__ Cmat, int t0) {
  __shared__ short ldsA[128 * 64];
  __shared__ short ldsB[128 * 64];
  const int tid = threadIdx.x, lane = tid & 63, wv = tid >> 6;
  const int wm = wv >> 1, wn = wv & 1;
  const int r0 = blockIdx.x * 128;
  const size_t brow0 = (size_t)blockIdx.y * 128;
  f32x4 acc[4][4] = {};

  for (int kk = 0; kk < Hdim; kk += 64) {
#pragma unroll
    for (int p = 0; p < 4; ++p) {
      int slot = ((wv * 4 + p) << 6) + lane;
      int m = slot >> 3, gp = slot & 7;
      int gl = gp ^ (m & 7);
      int r = r0 + m;                      // chunk-local row
      size_t arow = ((size_t)(r >> 6) * Tlen + t0 + (r & 63)) * Hdim;
      gld_lds16(A + arow + kk + (gl << 3), &ldsA[(wv * 4 + p) << 9]);
      gld_lds16(Bt + (brow0 + m) * Hdim + kk + (gl << 3), &ldsB[(wv * 4 + p) << 9]);
    }
    __syncthreads();
#pragma unroll
    for (int kh = 0; kh < 2; ++kh) {
      short8v af[4], bfv[4];
      const int gl = (kh << 2) + (lane >> 4);
#pragma unroll
      for (int mt = 0; mt < 4; ++mt) {
        int m = wm * 64 + mt * 16 + (lane & 15);
        af[mt] = *(const short8v*)&ldsA[m * 64 + ((gl ^ (m & 7)) << 3)];
      }
#pragma unroll
      for (int nt = 0; nt < 4; ++nt) {
        int n = wn * 64 + nt * 16 + (lane & 15);
        bfv[nt] = *(const short8v*)&ldsB[n * 64 + ((gl ^ (n & 7)) << 3)];
      }
#pragma unroll
      for (int mt = 0; mt < 4; ++mt)
#pragma unroll
        for (int nt = 0; nt < 4; ++nt)
          acc[mt][nt] = __builtin_amdgcn_mfma_f32_16x16x32_bf16(af[mt], bfv[nt], acc[mt][nt], 0, 0, 0);
    }
    __syncthreads();
  }
#pragma unroll
  for (int mt = 0; mt < 4; ++mt)
#pragma unroll
    for (int nt = 0; nt < 4; ++nt)
#pragma unroll
      for (int q = 0; q < 4; ++q) {
        size_t row = (size_t)r0 + wm * 64 + mt * 16 + ((lane >> 4) << 2) + q;
        size_t col = brow0 + wn * 64 + nt * 16 + (lane & 15);
        Cmat[row * NH6 + col] = f2bf(acc[mt][nt][q]);
      }
}

// ---------------------------------------------------------------------------
// Per-row-group grid barrier (128 WGs/group), monotone flags, agent fences.
DEVINL void grid_bar(unsigned int* flags, int grp, int gbid, unsigned int target, int tid) {
  __syncthreads();  // each thread drains its own global stores before signal
  if (tid == 0) {
    __builtin_amdgcn_fence(__ATOMIC_RELEASE, "agent");
    __hip_atomic_store(&flags[grp * 128 + gbid], target, __ATOMIC_RELAXED,
                       __HIP_MEMORY_SCOPE_AGENT);
  }
  if (tid < 64) {
    const int i0 = grp * 128 + (tid << 1);
    for (;;) {
      unsigned int a = __hip_atomic_load(&flags[i0 + 0], __ATOMIC_RELAXED, __HIP_MEMORY_SCOPE_AGENT);
      unsigned int b = __hip_atomic_load(&flags[i0 + 1], __ATOMIC_RELAXED, __HIP_MEMORY_SCOPE_AGENT);
      if (__all(a >= target && b >= target)) break;
      __builtin_amdgcn_s_sleep(1);
    }
  }
  __syncthreads();
  __builtin_amdgcn_fence(__ATOMIC_ACQUIRE, "agent");
}

// ---------------------------------------------------------------------------
// Persistent recurrent scan, one TCH-step chunk. 256 WGs x 256 threads.
// WG (grp, gbid): batch rows grp*32..+31, hidden units gbid*8..+7.
__launch_bounds__(256, 1)
__global__ void k_scan(const short* __restrict__ pi, const short* __restrict__ WsT,
                       const void* __restrict__ bs, void* __restrict__ ybase, int yext,
                       void* __restrict__ outb, int fhoff, int fcoff,
                       short* hb0, short* hb1, float* cbuf,
                       unsigned int* flags, int flagbase, int t0, int isfirst,
                       const int* __restrict__ lengths, const int* __restrict__ dflag) {
  extern __shared__ short smem[];
  short* Wt = smem;                                   // 48*1032 shorts
  float* psred = (float*)(smem + 48 * 1032);          // 24*256 floats

  const int tid  = threadIdx.x, lane = tid & 63, wv = tid >> 6;
  const int bid  = blockIdx.x, grp = bid >> 7, gbid = bid & 127;
  const int rb0  = grp * 32;
  const int u0   = gbid * 8;
  const int f32io = *dflag;
  const int yf32  = yext & f32io;

  // --- one-time: weight slice to LDS (cols packed n = gate*8 + unit)
  for (int n = 0; n < 40; ++n) {
    const short* src = WsT + (size_t)((n >> 3) * Hdim + u0 + (n & 7)) * Hdim;
    *(short4v*)&Wt[n * 1032 + tid * 4] = *(const short4v*)&src[tid * 4];
  }
  short4v zz = {0, 0, 0, 0};
  for (int n = 40; n < 48; ++n) *(short4v*)&Wt[n * 1032 + tid * 4] = zz;

  const int grow = tid >> 3, gunit = tid & 7;
  const int gb = rb0 + grow;
  const int mylen = lengths[gb];
  const int gmax  = lengths[rb0];                     // group max (sorted desc)
  const size_t sidx = (size_t)gb * Hdim + u0 + gunit;

  float bias[5];
  int   psoff[5];
#pragma unroll
  for (int g = 0; g < 5; ++g) {
    bias[g] = f32io ? ((const float*)bs)[g * Hdim + u0 + gunit]
                    : bf2f(((const short*)bs)[g * Hdim + u0 + gunit]);
    int n = g * 8 + gunit, nt = n >> 4, cl = n & 15;
    int mt = grow >> 4, rw = grow & 15;
    int ln = ((rw >> 2) << 4) | cl, reg = rw & 3;
    psoff[g] = ((mt * 3 + nt) << 8) + (ln << 2) + reg;
  }

  float c_state, h_state;
  if (isfirst) {
    c_state = 0.0f; h_state = 0.0f;
    hb0[sidx] = 0;
  } else {
    c_state = cbuf[sidx];
    h_state = bf2f(hb0[sidx]);                        // t0 even -> hb0 = h(t0-1)
  }
  if (isfirst) grid_bar(flags, grp, gbid, (unsigned)(flagbase + 1), tid);

  short* hbufs[2] = {hb0, hb1};
  for (int t = t0; t < t0 + TCH; ++t) {
    const short* hcur = hbufs[t & 1];
    short* hnext      = hbufs[(t + 1) & 1];

    const short* pib = pi + (size_t)(gb * TCH + (t - t0)) * NH6 + u0 + gunit;
    float piv[6];
#pragma unroll
    for (int g = 0; g < 6; ++g) piv[g] = bf2f(pib[g << 10]);

    // recurrent GEMM, K split across 4 waves
    f32x4 acc[2][3] = {};
    const int kb = wv << 8;
#pragma unroll
    for (int ks = 0; ks < 8; ++ks) {
      const int k = kb + (ks << 5) + ((lane >> 4) << 3);
      short8v a0 = *(const short8v*)&hcur[(size_t)(rb0 +      (lane & 15)) * Hdim + k];
      short8v a1 = *(const short8v*)&hcur[(size_t)(rb0 + 16 + (lane & 15)) * Hdim + k];
#pragma unroll
      for (int nt = 0; nt < 3; ++nt) {
        short8v bfv = *(const short8v*)&Wt[(nt * 16 + (lane & 15)) * 1032 + k];
        acc[0][nt] = __builtin_amdgcn_mfma_f32_16x16x32_bf16(a0, bfv, acc[0][nt], 0, 0, 0);
        acc[1][nt] = __builtin_amdgcn_mfma_f32_16x16x32_bf16(a1, bfv, acc[1][nt], 0, 0, 0);
      }
    }
#pragma unroll
    for (int mt = 0; mt < 2; ++mt)
#pragma unroll
      for (int nt = 0; nt < 3; ++nt)
        *(f32x4*)&psred[((wv * 6 + mt * 3 + nt) << 8) + (lane << 2)] = acc[mt][nt];
    __syncthreads();

    float ps[5];
#pragma unroll
    for (int g = 0; g < 5; ++g) {
      int o = psoff[g];
      ps[g] = bias[g] + psred[o] + psred[1536 + o] + psred[3072 + o] + psred[4608 + o];
    }
    float ig = sigm(piv[0] + ps[0]);
    float fg = sigm(piv[1] + ps[1]);
    float mg = tanh_(piv[2] + ps[2]);
    float og = sigm(piv[3] + ps[3]);
    float hw = sigm(piv[4] + ps[4]);
    float cn  = ig * mg + fg * c_state;
    float outv = og * tanh_(cn);
    outv = hw * outv + (1.0f - hw) * piv[5];
    const bool valid = (t < mylen);
    if (valid) { c_state = cn; h_state = outv; }

    size_t yi = ((size_t)gb * Tlen + t) * Hdim + u0 + gunit;
    if (yf32) ((float*)ybase)[yi] = valid ? outv : 0.0f;
    else      ((short*)ybase)[yi] = valid ? f2bf(outv) : (short)0;
    hnext[sidx] = f2bf(h_state);

    // skip barrier once the whole group is frozen (writes become value-equal)
    if (t + 1 < t0 + TCH && t < gmax)
      grid_bar(flags, grp, gbid, (unsigned)(flagbase + 2 + (t - t0)), tid);
  }

  cbuf[sidx] = c_state;
  if (f32io) {
    ((float*)outb)[fhoff + sidx] = h_state;
    ((float*)outb)[fcoff + sidx] = c_state;
  } else {
    ((short*)outb)[fhoff + sidx] = f2bf(h_state);
    ((short*)outb)[fcoff + sidx] = f2bf(c_state);
  }
}

// ---------------------------------------------------------------------------
extern "C" void kernel_launch(void* const* d_in, const int* in_sizes, int n_in,
                              void* d_out, int out_size, void* d_ws, size_t ws_size,
                              hipStream_t stream) {
  const void* x       = d_in[0];
  const int*  lengths = (const int*)d_in[1];
  const void* Wi0     = d_in[2];
  const void* Ws0     = d_in[3];
  const void* bs0     = d_in[4];
  const void* Wi1     = d_in[5];
  const void* Ws1     = d_in[6];
  const void* bs1     = d_in[7];
  char* ws = (char*)d_ws;

  short* xbf   = (short*)(ws + WS_XBF);
  short* y0    = (short*)(ws + WS_Y0);
  short* WiT0  = (short*)(ws + WS_WIT0);
  short* WiT1  = (short*)(ws + WS_WIT1);
  short* WsT0  = (short*)(ws + WS_WST0);
  short* WsT1  = (short*)(ws + WS_WST1);
  short* pibuf = (short*)(ws + WS_PI);
  short* hb0   = (short*)(ws + WS_HB0);
  short* hb1   = (short*)(ws + WS_HB1);
  float* cbuf  = (float*)(ws + WS_CB);
  unsigned int* flags = (unsigned int*)(ws + WS_FLAGS);
  int*   dflag = (int*)(ws + WS_DFLAG);

  k_detect<<<1, 256, 0, stream>>>((const short*)x, flags, dflag);
  k_convert<<<2048, 256, 0, stream>>>(x, xbf, dflag);
  k_transpose<<<dim3(16, 96), 256, 0, stream>>>(Wi0, WiT0, 1024, NH6, dflag);
  k_transpose<<<dim3(16, 80), 256, 0, stream>>>(Ws0, WsT0, 1024, NH5, dflag);
  k_transpose<<<dim3(16, 96), 256, 0, stream>>>(Wi1, WiT1, 1024, NH6, dflag);
  k_transpose<<<dim3(16, 80), 256, 0, stream>>>(Ws1, WsT1, 1024, NH5, dflag);

  const unsigned int scan_lds = 48 * 1032 * 2 + 24 * 256 * 4;  // 123,648 B
  hipFuncSetAttribute((const void*)k_scan, hipFuncAttributeMaxDynamicSharedMemorySize,
                      (int)scan_lds);

  for (int layer = 0; layer < 2; ++layer) {
    const short* Asrc = (layer == 0) ? xbf : y0;
    const short* WiT  = (layer == 0) ? WiT0 : WiT1;
    const short* WsT  = (layer == 0) ? WsT0 : WsT1;
    const void*  bsp  = (layer == 0) ? bs0 : bs1;
    for (int c = 0; c < NCH; ++c) {
      k_gemm<<<dim3(32, 48), 256, 0, stream>>>(Asrc, WiT, pibuf, c * TCH);

      const short* pi_p = pibuf; const short* ws_p = WsT; const void* bs_p = bsp;
      void* y_p  = (layer == 0) ? (void*)y0 : d_out;
      int yext   = (layer == 0) ? 0 : 1;
      void* outp = d_out;
      int fh = OUT_FH + layer * 65536, fcv = OUT_FC + layer * 65536;
      short* h0 = hb0; short* h1 = hb1; float* cb = cbuf;
      unsigned int* fl = flags;
      int fb = (layer * NCH + c) * 65;
      int tt0 = c * TCH;
      int isf = (c == 0) ? 1 : 0;
      const int* len = lengths; const int* df = dflag;
      void* args[17] = {&pi_p, &ws_p, &bs_p, &y_p, &yext, &outp, &fh, &fcv,
                        &h0, &h1, &cb, &fl, &fb, &tt0, &isf, &len, &df};
      hipLaunchCooperativeKernel((void*)k_scan, dim3(256), dim3(256), args,
                                 scan_lds, stream);
    }
  }
}

// Round 3
// 10916.102 us; speedup vs baseline: 1.6096x; 1.6096x over previous
//
#include <hip/hip_runtime.h>

// ---------------------------------------------------------------------------
// StackedLstm: 2-layer highway LSTM, B=64, T=512, D=H=1024 (bf16 I/O)
// Recurrence sync: tagged-h dataflow (no grid barriers, no fences).
// h value+step packed in one dword, exchanged via agent-scope atomics (LLC).
// ---------------------------------------------------------------------------

#define DEVINL __device__ __forceinline__

typedef short short8v __attribute__((ext_vector_type(8)));
typedef short short4v __attribute__((ext_vector_type(4)));
typedef float f32x4 __attribute__((ext_vector_type(4)));

#define Bsz   64
#define Tlen  512
#define Hdim  1024
#define NH5   5120
#define NH6   6144
#define TCH   64          // time-chunk length
#define NCH   8           // chunks per layer
#define XELT  33554432    // B*T*H elements

// d_out element offsets: y1 [B,T,H] | final_h [2,B,H] | final_c [2,B,H]
#define OUT_FH 33554432
#define OUT_FC 33685504

// workspace byte offsets (total ~233.1 MB)
#define WS_XBF    0ULL
#define WS_Y0     67108864ULL
#define WS_WIT0   134217728ULL
#define WS_WIT1   146800640ULL
#define WS_WST0   159383552ULL
#define WS_WST1   169869312ULL
#define WS_PI     180355072ULL
#define WS_HW0    230686720ULL   // 4 slots x 64 x 1024 dwords = 1 MB
#define WS_HW1    231735296ULL   // 1 MB
#define WS_CB     232783872ULL   // 256 KB fp32 c-state
#define WS_DFLAG  233046016ULL

DEVINL short f2bf(float f) {
  unsigned int u = __builtin_bit_cast(unsigned int, f);
  u += 0x7fffu + ((u >> 16) & 1u);          // round-to-nearest-even
  return (short)(u >> 16);
}
DEVINL float bf2f(short s) {
  unsigned int u = ((unsigned int)(unsigned short)s) << 16;
  return __builtin_bit_cast(float, u);
}
DEVINL float fexp2(float x) { return __builtin_amdgcn_exp2f(x); }
DEVINL float frcp(float x)  { return __builtin_amdgcn_rcpf(x); }
DEVINL float sigm(float x)  { return frcp(1.0f + fexp2(-1.44269504f * x)); }
DEVINL float tanh_(float x) { return 1.0f - 2.0f * frcp(1.0f + fexp2(2.88539008f * x)); }

DEVINL void gld_lds16(const short* g, short* lds) {
  __builtin_amdgcn_global_load_lds(
      (const __attribute__((address_space(1))) void*)g,
      (__attribute__((address_space(3))) void*)lds, 16, 0, 0);
}

DEVINL unsigned long long ald64(const unsigned long long* p) {
  return __hip_atomic_load(p, __ATOMIC_RELAXED, __HIP_MEMORY_SCOPE_AGENT);
}
DEVINL unsigned int ald32(const unsigned int* p) {
  return __hip_atomic_load(p, __ATOMIC_RELAXED, __HIP_MEMORY_SCOPE_AGENT);
}
DEVINL void ast32(unsigned int* p, unsigned int v) {
  __hip_atomic_store(p, v, __ATOMIC_RELAXED, __HIP_MEMORY_SCOPE_AGENT);
}

// ---------------------------------------------------------------------------
// Detect input dtype (bf16 never has exp==0xFF in N(0,1) data) -> dflag.
__global__ void k_detect(const short* __restrict__ x, int* dflag) {
  __shared__ int found;
  if (threadIdx.x == 0) found = 0;
  __syncthreads();
  int hit = 0;
  for (int i = threadIdx.x; i < 16384; i += 256) {
    unsigned int u = (unsigned short)x[i];
    if ((u & 0x7F80u) == 0x7F80u) hit = 1;
  }
  if (hit) atomicOr(&found, 1);
  __syncthreads();
  if (threadIdx.x == 0) *dflag = found;
}

// Zero both tagged-h rings (tags -> 0, h -> +0.0). Agent stores so readers'
// L2-bypassing loads are guaranteed to see them.
__global__ void k_init(unsigned int* hw0, unsigned int* hw1) {
  const int i = (blockIdx.x * 256 + threadIdx.x) * 4;
#pragma unroll
  for (int j = 0; j < 4; ++j) { ast32(hw0 + i + j, 0u); ast32(hw1 + i + j, 0u); }
}

// x -> bf16 copy (converting from fp32 if detected)
__global__ void k_convert(const void* __restrict__ xin, short* __restrict__ xbf,
                          const int* __restrict__ dflag) {
  const int f32 = *dflag;
  const size_t stride = (size_t)gridDim.x * 1024;
  size_t i = ((size_t)blockIdx.x * 256 + threadIdx.x) * 4;
  for (; i < (size_t)XELT; i += stride) {
    short4v v;
    if (f32) {
      const float4 f = *(const float4*)&((const float*)xin)[i];
      v[0] = f2bf(f.x); v[1] = f2bf(f.y); v[2] = f2bf(f.z); v[3] = f2bf(f.w);
    } else {
      v = *(const short4v*)&((const short*)xin)[i];
    }
    *(short4v*)&xbf[i] = v;
  }
}

// (R,C) -> (C,R) bf16 output, dtype-flagged input, 64x64 tiles
__global__ void k_transpose(const void* __restrict__ in, short* __restrict__ out,
                            int R, int C, const int* __restrict__ dflag) {
  __shared__ short tile[64][65];
  const int f32 = *dflag;
  const int r0 = blockIdx.x << 6, c0 = blockIdx.y << 6;
  const int tid = threadIdx.x;
#pragma unroll
  for (int it = 0; it < 8; ++it) {
    int idx = (it << 8) + tid;
    int r = idx >> 5, c2 = (idx & 31) << 1;
    if (f32) {
      const float* inF = (const float*)in;
      tile[r][c2]     = f2bf(inF[(size_t)(r0 + r) * C + c0 + c2]);
      tile[r][c2 + 1] = f2bf(inF[(size_t)(r0 + r) * C + c0 + c2 + 1]);
    } else {
      int v = *(const int*)&((const short*)in)[(size_t)(r0 + r) * C + c0 + c2];
      tile[r][c2]     = (short)(v & 0xffff);
      tile[r][c2 + 1] = (short)(((unsigned)v) >> 16);
    }
  }
  __syncthreads();
#pragma unroll
  for (int it = 0; it < 8; ++it) {
    int idx = (it << 8) + tid;
    int rr = idx >> 5, k2 = (idx & 31) << 1;
    unsigned int lo = (unsigned short)tile[k2][rr];
    unsigned int hi = (unsigned short)tile[k2 + 1][rr];
    *(unsigned int*)&out[(size_t)(c0 + rr) * R + r0 + k2] = lo | (hi << 16);
  }
}

// ---------------------------------------------------------------------------
// pi_chunk[r, 0:6144] = A[row(r), :] @ Bt^T, rows map the chunk's (b, t0+tt).
__launch_bounds__(256)
__global__ void k_gemm(const short* __restrict__ A, const short* __restrict__ Bt,
                       short* __restrict__ Cmat, int t0) {
  __shared__ short ldsA[128 * 64];
  __shared__ short ldsB[128 * 64];
  const int tid = threadIdx.x, lane = tid & 63, wv = tid >> 6;
  const int wm = wv >> 1, wn = wv & 1;
  const int r0 = blockIdx.x * 128;
  const size_t brow0 = (size_t)blockIdx.y * 128;
  f32x4 acc[4][4] = {};

  for (int kk = 0; kk < Hdim; kk += 64) {
#pragma unroll
    for (int p = 0; p < 4; ++p) {
      int slot = ((wv * 4 + p) << 6) + lane;
      int m = slot >> 3, gp = slot & 7;
      int gl = gp ^ (m & 7);
      int r = r0 + m;
      size_t arow = ((size_t)(r >> 6) * Tlen + t0 + (r & 63)) * Hdim;
      gld_lds16(A + arow + kk + (gl << 3), &ldsA[(wv * 4 + p) << 9]);
      gld_lds16(Bt + (brow0 + m) * Hdim + kk + (gl << 3), &ldsB[(wv * 4 + p) << 9]);
    }
    __syncthreads();
#pragma unroll
    for (int kh = 0; kh < 2; ++kh) {
      short8v af[4], bfv[4];
      const int gl = (kh << 2) + (lane >> 4);
#pragma unroll
      for (int mt = 0; mt < 4; ++mt) {
        int m = wm * 64 + mt * 16 + (lane & 15);
        af[mt] = *(const short8v*)&ldsA[m * 64 + ((gl ^ (m & 7)) << 3)];
      }
#pragma unroll
      for (int nt = 0; nt < 4; ++nt) {
        int n = wn * 64 + nt * 16 + (lane & 15);
        bfv[nt] = *(const short8v*)&ldsB[n * 64 + ((gl ^ (n & 7)) << 3)];
      }
#pragma unroll
      for (int mt = 0; mt < 4; ++mt)
#pragma unroll
        for (int nt = 0; nt < 4; ++nt)
          acc[mt][nt] = __builtin_amdgcn_mfma_f32_16x16x32_bf16(af[mt], bfv[nt], acc[mt][nt], 0, 0, 0);
    }
    __syncthreads();
  }
#pragma unroll
  for (int mt = 0; mt < 4; ++mt)
#pragma unroll
    for (int nt = 0; nt < 4; ++nt)
#pragma unroll
      for (int q = 0; q < 4; ++q) {
        size_t row = (size_t)r0 + wm * 64 + mt * 16 + ((lane >> 4) << 2) + q;
        size_t col = brow0 + wn * 64 + nt * 16 + (lane & 15);
        Cmat[row * NH6 + col] = f2bf(acc[mt][nt][q]);
      }
}

// ---------------------------------------------------------------------------
// Persistent recurrent scan, one TCH-step chunk. 256 WGs x 256 threads.
// WG (grp, gbid): batch rows grp*32..+31, hidden units gbid*8..+7.
// h ring: hw[4][64][1024] dwords, dword = (bf16 h << 16) | ((t+1) & 0xFFFF).
__launch_bounds__(256, 1)
__global__ void k_scan(const short* __restrict__ pi, const short* __restrict__ WsT,
                       const void* __restrict__ bs, void* __restrict__ ybase, int yext,
                       void* __restrict__ outb, int fhoff, int fcoff,
                       unsigned int* hw, float* cbuf,
                       int t0, int isfirst,
                       const int* __restrict__ lengths, const int* __restrict__ dflag) {
  extern __shared__ short smem[];
  short* Wt = smem;                                   // 48*1032 shorts
  float* psred = (float*)(smem + 48 * 1032);          // 24*256 floats

  const int tid  = threadIdx.x, lane = tid & 63, wv = tid >> 6;
  const int bid  = blockIdx.x, grp = bid >> 7, gbid = bid & 127;
  const int rb0  = grp * 32;
  const int u0   = gbid * 8;
  const int f32io = *dflag;
  const int yf32  = yext & f32io;

  // --- one-time: weight slice to LDS (cols packed n = gate*8 + unit)
  for (int n = 0; n < 40; ++n) {
    const short* src = WsT + (size_t)((n >> 3) * Hdim + u0 + (n & 7)) * Hdim;
    *(short4v*)&Wt[n * 1032 + tid * 4] = *(const short4v*)&src[tid * 4];
  }
  short4v zz = {0, 0, 0, 0};
  for (int n = 40; n < 48; ++n) *(short4v*)&Wt[n * 1032 + tid * 4] = zz;

  const int grow = tid >> 3, gunit = tid & 7;
  const int gb = rb0 + grow;
  const int mylen = lengths[gb];
  const unsigned int selfoff = ((unsigned)gb << 10) | (unsigned)(u0 + gunit);

  float bias[5];
  int   psoff[5];
#pragma unroll
  for (int g = 0; g < 5; ++g) {
    bias[g] = f32io ? ((const float*)bs)[g * Hdim + u0 + gunit]
                    : bf2f(((const short*)bs)[g * Hdim + u0 + gunit]);
    int n = g * 8 + gunit, nt = n >> 4, cl = n & 15;
    int mt = grow >> 4, rw = grow & 15;
    int ln = ((rw >> 2) << 4) | cl, reg = rw & 3;
    psoff[g] = ((mt * 3 + nt) << 8) + (ln << 2) + reg;
  }

  // restore own state: h from ring slot (t0-1)&3 (zeros if first), c from cbuf
  float h_state = bf2f((short)(ald32(hw + (((unsigned)(t0 + 3) & 3) << 16) + selfoff) >> 16));
  float c_state = isfirst ? 0.0f : cbuf[(size_t)gb * Hdim + u0 + gunit];

  for (int t = t0; t < t0 + TCH; ++t) {
    const unsigned long long* hs =
        (const unsigned long long*)hw + ((size_t)((t + 3) & 3) << 15);
    const unsigned int want = (unsigned)(t & 0xFFFF);

    // pi loads (independent of h; issue early)
    const short* pib = pi + (size_t)(gb * TCH + (t - t0)) * NH6 + u0 + gunit;
    float piv[6];
#pragma unroll
    for (int g = 0; g < 6; ++g) piv[g] = bf2f(pib[g << 10]);

    // --- recurrent GEMM, K split across 4 waves; tagged-h poll per K-chunk
    f32x4 acc[2][3] = {};
    const int kb = wv << 8;
#pragma unroll
    for (int ks = 0; ks < 8; ++ks) {
      const int k = kb + (ks << 5) + ((lane >> 4) << 3);      // dword index
      const unsigned long long* p0 = hs + (((size_t)(rb0 + (lane & 15))) << 9) + (k >> 1);
      const unsigned long long* p1 = p0 + (16 << 9);
      unsigned long long q0, q1, q2, q3, q4, q5, q6, q7;
      bool ok;
      do {
        q0 = ald64(p0);     q1 = ald64(p0 + 1); q2 = ald64(p0 + 2); q3 = ald64(p0 + 3);
        q4 = ald64(p1);     q5 = ald64(p1 + 1); q6 = ald64(p1 + 2); q7 = ald64(p1 + 3);
        unsigned long long m = q0 & q1 & q2 & q3 & q4 & q5 & q6 & q7;
        unsigned long long x = q0 | q1 | q2 | q3 | q4 | q5 | q6 | q7;
        // all 16 tags equal `want` iff AND and OR of tag fields both equal it
        ok = ((unsigned)(m & 0xFFFF) == want) & ((unsigned)((m >> 32) & 0xFFFF) == want) &
             ((unsigned)(x & 0xFFFF) == want) & ((unsigned)((x >> 32) & 0xFFFF) == want);
      } while (!ok);
      short8v a0, a1;
      a0[0] = (short)(q0 >> 16); a0[1] = (short)(q0 >> 48);
      a0[2] = (short)(q1 >> 16); a0[3] = (short)(q1 >> 48);
      a0[4] = (short)(q2 >> 16); a0[5] = (short)(q2 >> 48);
      a0[6] = (short)(q3 >> 16); a0[7] = (short)(q3 >> 48);
      a1[0] = (short)(q4 >> 16); a1[1] = (short)(q4 >> 48);
      a1[2] = (short)(q5 >> 16); a1[3] = (short)(q5 >> 48);
      a1[4] = (short)(q6 >> 16); a1[5] = (short)(q6 >> 48);
      a1[6] = (short)(q7 >> 16); a1[7] = (short)(q7 >> 48);
#pragma unroll
      for (int nt = 0; nt < 3; ++nt) {
        short8v bfv = *(const short8v*)&Wt[(nt * 16 + (lane & 15)) * 1032 + k];
        acc[0][nt] = __builtin_amdgcn_mfma_f32_16x16x32_bf16(a0, bfv, acc[0][nt], 0, 0, 0);
        acc[1][nt] = __builtin_amdgcn_mfma_f32_16x16x32_bf16(a1, bfv, acc[1][nt], 0, 0, 0);
      }
    }
#pragma unroll
    for (int mt = 0; mt < 2; ++mt)
#pragma unroll
      for (int nt = 0; nt < 3; ++nt)
        *(f32x4*)&psred[((wv * 6 + mt * 3 + nt) << 8) + (lane << 2)] = acc[mt][nt];
    __syncthreads();

    float ps[5];
#pragma unroll
    for (int g = 0; g < 5; ++g) {
      int o = psoff[g];
      ps[g] = bias[g] + psred[o] + psred[1536 + o] + psred[3072 + o] + psred[4608 + o];
    }
    float ig = sigm(piv[0] + ps[0]);
    float fg = sigm(piv[1] + ps[1]);
    float mg = tanh_(piv[2] + ps[2]);
    float og = sigm(piv[3] + ps[3]);
    float hw_g = sigm(piv[4] + ps[4]);
    float cn  = ig * mg + fg * c_state;
    float outv = og * tanh_(cn);
    outv = hw_g * outv + (1.0f - hw_g) * piv[5];
    const bool valid = (t < mylen);
    if (valid) { c_state = cn; h_state = outv; }

    size_t yi = ((size_t)gb * Tlen + t) * Hdim + u0 + gunit;
    if (yf32) ((float*)ybase)[yi] = valid ? outv : 0.0f;
    else      ((short*)ybase)[yi] = valid ? f2bf(outv) : (short)0;

    // publish h(t) tagged t+1 into ring slot t&3 (atomic dword: tag+data together)
    unsigned int pk = (((unsigned)(unsigned short)f2bf(h_state)) << 16) |
                      ((unsigned)((t + 1) & 0xFFFF));
    ast32(hw + (((unsigned)t & 3) << 16) + selfoff, pk);

    __syncthreads();   // protect psred reuse next step
  }

  cbuf[(size_t)gb * Hdim + u0 + gunit] = c_state;
  const size_t sidx = (size_t)gb * Hdim + u0 + gunit;
  if (f32io) {
    ((float*)outb)[fhoff + sidx] = h_state;
    ((float*)outb)[fcoff + sidx] = c_state;
  } else {
    ((short*)outb)[fhoff + sidx] = f2bf(h_state);
    ((short*)outb)[fcoff + sidx] = f2bf(c_state);
  }
}

// ---------------------------------------------------------------------------
extern "C" void kernel_launch(void* const* d_in, const int* in_sizes, int n_in,
                              void* d_out, int out_size, void* d_ws, size_t ws_size,
                              hipStream_t stream) {
  const void* x       = d_in[0];
  const int*  lengths = (const int*)d_in[1];
  const void* Wi0     = d_in[2];
  const void* Ws0     = d_in[3];
  const void* bs0     = d_in[4];
  const void* Wi1     = d_in[5];
  const void* Ws1     = d_in[6];
  const void* bs1     = d_in[7];
  char* ws = (char*)d_ws;

  short* xbf   = (short*)(ws + WS_XBF);
  short* y0    = (short*)(ws + WS_Y0);
  short* WiT0  = (short*)(ws + WS_WIT0);
  short* WiT1  = (short*)(ws + WS_WIT1);
  short* WsT0  = (short*)(ws + WS_WST0);
  short* WsT1  = (short*)(ws + WS_WST1);
  short* pibuf = (short*)(ws + WS_PI);
  unsigned int* hw0 = (unsigned int*)(ws + WS_HW0);
  unsigned int* hw1 = (unsigned int*)(ws + WS_HW1);
  float* cbuf  = (float*)(ws + WS_CB);
  int*   dflag = (int*)(ws + WS_DFLAG);

  k_detect<<<1, 256, 0, stream>>>((const short*)x, dflag);
  k_init<<<256, 256, 0, stream>>>(hw0, hw1);
  k_convert<<<2048, 256, 0, stream>>>(x, xbf, dflag);
  k_transpose<<<dim3(16, 96), 256, 0, stream>>>(Wi0, WiT0, 1024, NH6, dflag);
  k_transpose<<<dim3(16, 80), 256, 0, stream>>>(Ws0, WsT0, 1024, NH5, dflag);
  k_transpose<<<dim3(16, 96), 256, 0, stream>>>(Wi1, WiT1, 1024, NH6, dflag);
  k_transpose<<<dim3(16, 80), 256, 0, stream>>>(Ws1, WsT1, 1024, NH5, dflag);

  const unsigned int scan_lds = 48 * 1032 * 2 + 24 * 256 * 4;  // 123,648 B
  hipFuncSetAttribute((const void*)k_scan, hipFuncAttributeMaxDynamicSharedMemorySize,
                      (int)scan_lds);

  for (int layer = 0; layer < 2; ++layer) {
    const short* Asrc = (layer == 0) ? xbf : y0;
    const short* WiT  = (layer == 0) ? WiT0 : WiT1;
    const short* WsT  = (layer == 0) ? WsT0 : WsT1;
    const void*  bsp  = (layer == 0) ? bs0 : bs1;
    unsigned int* hwp = (layer == 0) ? hw0 : hw1;
    for (int c = 0; c < NCH; ++c) {
      k_gemm<<<dim3(32, 48), 256, 0, stream>>>(Asrc, WiT, pibuf, c * TCH);

      const short* pi_p = pibuf; const short* ws_p = WsT; const void* bs_p = bsp;
      void* y_p  = (layer == 0) ? (void*)y0 : d_out;
      int yext   = (layer == 0) ? 0 : 1;
      void* outp = d_out;
      int fh = OUT_FH + layer * 65536, fcv = OUT_FC + layer * 65536;
      unsigned int* hwq = hwp; float* cb = cbuf;
      int tt0 = c * TCH;
      int isf = (c == 0) ? 1 : 0;
      const int* len = lengths; const int* df = dflag;
      void* args[14] = {&pi_p, &ws_p, &bs_p, &y_p, &yext, &outp, &fh, &fcv,
                        &hwq, &cb, &tt0, &isf, &len, &df};
      hipLaunchCooperativeKernel((void*)k_scan, dim3(256), dim3(256), args,
                                 scan_lds, stream);
    }
  }
}